// Round 1
// baseline (313.570 us; speedup 1.0000x reference)
//
#include <hip/hip_runtime.h>
#include <math.h>

// Problem constants (from reference)
constexpr int Bc   = 256;      // batch
constexpr int KP1  = 4097;     // K negatives + 1
constexpr int Dc   = 128;      // feature dim
constexpr int NROW = 1000000;  // memory bank rows
constexpr float MOM = 0.5f;
constexpr float Tc  = 0.07f;

// ---------------------------------------------------------------------------
// Kernel 1: stream-copy the memory bank into the output region (float4).
// 1 GB of traffic -> pure HBM BW.
__global__ __launch_bounds__(256) void copy_mem_kernel(const float4* __restrict__ src,
                                                       float4* __restrict__ dst,
                                                       int n4) {
    int i = blockIdx.x * 256 + threadIdx.x;
    const int stride = gridDim.x * 256;
    for (; i < n4; i += stride) dst[i] = src[i];
}

// ---------------------------------------------------------------------------
// Kernel 2: momentum scatter-update of rows y[b] (overwrites the copy).
// One wave (64 lanes) per b; float2 per lane covers D=128.
// Last-write-wins for duplicate y (numpy scatter semantics).
__global__ __launch_bounds__(64) void scatter_kernel(const float* __restrict__ memory,
                                                     const float* __restrict__ ab,
                                                     const int* __restrict__ y,
                                                     float* __restrict__ out_mem) {
    const int b = blockIdx.x;
    const int row = y[b];
    for (int b2 = b + 1; b2 < Bc; ++b2)
        if (y[b2] == row) return;  // a later b writes this row; numpy: last wins

    const int lane = threadIdx.x;  // 0..63
    float2 m = *(const float2*)(memory + (size_t)row * Dc + lane * 2);
    float2 a = *(const float2*)(ab + b * Dc + lane * 2);
    float v0 = m.x * MOM + a.x * (1.0f - MOM);
    float v1 = m.y * MOM + a.y * (1.0f - MOM);
    float s = v0 * v0 + v1 * v1;
#pragma unroll
    for (int off = 32; off; off >>= 1) s += __shfl_xor(s, off);
    const float inv = 1.0f / sqrtf(s);
    float2 o;
    o.x = v0 * inv;
    o.y = v1 * inv;
    *(float2*)(out_mem + (size_t)row * Dc + lane * 2) = o;
}

// ---------------------------------------------------------------------------
// Kernel 3: gather + 3 fused dot products.
// 8 lanes per (b,k): each lane loads 4x float4 (64B contiguous per 8-lane
// group), queries preloaded into registers, 3-step shfl_xor reduce.
__global__ __launch_bounds__(256) void gather_dot_kernel(
    const float* __restrict__ memory,
    const float* __restrict__ ab,
    const float* __restrict__ l,
    const float* __restrict__ ss,
    const int* __restrict__ idx,
    float* __restrict__ out) {
    const int b    = blockIdx.x;
    const int lane = threadIdx.x & 63;
    const int wid  = (threadIdx.x >> 6) + (blockIdx.y << 2);  // wave id within b
    const int nw   = gridDim.y << 2;                          // total waves per b
    const int g    = lane >> 3;  // k-group 0..7
    const int sub  = lane & 7;   // lane within group

    // preload queries: lane needs float4 at d = it*32 + sub*4, it=0..3
    float4 qa[4], ql[4], qs[4];
#pragma unroll
    for (int it = 0; it < 4; ++it) {
        const int d = it * 32 + sub * 4;
        qa[it] = *(const float4*)(ab + b * Dc + d);
        ql[it] = *(const float4*)(l + b * Dc + d);
        qs[it] = *(const float4*)(ss + b * Dc + d);
    }
    const int* idxb = idx + (size_t)b * KP1;
    const size_t out_b = (size_t)b * KP1;
    const size_t plane = (size_t)Bc * KP1;

    for (int k0 = wid * 8; k0 < KP1; k0 += nw * 8) {
        const int k = k0 + g;
        const int kc = (k < KP1) ? k : (KP1 - 1);  // clamp; masked on write
        const int row = idxb[kc];
        const float* wrow = memory + (size_t)row * Dc;
        float sa = 0.f, sl = 0.f, s2 = 0.f;
#pragma unroll
        for (int it = 0; it < 4; ++it) {
            const float4 w = *(const float4*)(wrow + it * 32 + sub * 4);
            sa += w.x * qa[it].x + w.y * qa[it].y + w.z * qa[it].z + w.w * qa[it].w;
            sl += w.x * ql[it].x + w.y * ql[it].y + w.z * ql[it].z + w.w * ql[it].w;
            s2 += w.x * qs[it].x + w.y * qs[it].y + w.z * qs[it].z + w.w * qs[it].w;
        }
#pragma unroll
        for (int off = 1; off < 8; off <<= 1) {
            sa += __shfl_xor(sa, off);
            sl += __shfl_xor(sl, off);
            s2 += __shfl_xor(s2, off);
        }
        if (sub == 0 && k < KP1) {
            out[0 * plane + out_b + k] = sa / Tc;  // out_orig (ab)
            out[1 * plane + out_b + k] = sl / Tc;  // out_l
            out[2 * plane + out_b + k] = s2 / Tc;  // out_ss
        }
    }
}

// ---------------------------------------------------------------------------
extern "C" void kernel_launch(void* const* d_in, const int* in_sizes, int n_in,
                              void* d_out, int out_size, void* d_ws, size_t ws_size,
                              hipStream_t stream) {
    const float* ab     = (const float*)d_in[0];
    const float* l      = (const float*)d_in[1];
    const float* ss     = (const float*)d_in[2];
    const float* memory = (const float*)d_in[3];
    const int*   idx    = (const int*)d_in[4];
    const int*   y      = (const int*)d_in[5];

    float* out     = (float*)d_out;
    float* out_mem = out + (size_t)3 * Bc * KP1;

    const int n4 = (NROW * Dc) / 4;  // 32M float4
    copy_mem_kernel<<<dim3(2048), dim3(256), 0, stream>>>(
        (const float4*)memory, (float4*)out_mem, n4);
    scatter_kernel<<<dim3(Bc), dim3(64), 0, stream>>>(memory, ab, y, out_mem);
    gather_dot_kernel<<<dim3(Bc, 16), dim3(256), 0, stream>>>(memory, ab, l, ss, idx, out);
}